// Round 4
// baseline (381.261 us; speedup 1.0000x reference)
//
#include <hip/hip_runtime.h>

typedef __bf16 bf16x8 __attribute__((ext_vector_type(8)));
typedef float f32x4 __attribute__((ext_vector_type(4)));
typedef unsigned short u16;
typedef unsigned int u32;
typedef u16 u16x4 __attribute__((ext_vector_type(4)));
typedef u16 u16x8 __attribute__((ext_vector_type(8)));

#define L2ALPHA (-0.014499569f)   // log2(0.99)
#define WIN 1024                  // decay window

static __device__ __forceinline__ u16 f2bf(float f) {
    u32 u = __builtin_bit_cast(u32, f);
    return (u16)((u + 0x7FFFu + ((u >> 16) & 1u)) >> 16);
}

// async global->LDS, 16B per lane, dest must be wave-uniform-base + lane*16
static __device__ __forceinline__ void gl2lds16(const void* g, void* l) {
    __builtin_amdgcn_global_load_lds(
        (const __attribute__((address_space(1))) u32*)g,
        (__attribute__((address_space(3))) u32*)l, 16, 0, 0);
}

// ---------------------------------------------------------------------------
// Projection v4 (unchanged): one barrier total; W panel staged once;
// x staged wave-private each kt. K panel stored with EVEN/ODD key split.
// ---------------------------------------------------------------------------
__global__ __launch_bounds__(256, 2) void proj_kernel(
        const float* __restrict__ x, const float* __restrict__ Wq,
        const float* __restrict__ bias,
        u16* __restrict__ qb, u16* __restrict__ kb, u16* __restrict__ vb)
{
    __shared__ __align__(16) u16 Bs[32 * 128 * 8];   // 64 KB: [k8][col][e]
    __shared__ __align__(16) u16 As[4][32 * 40];     // 10 KB, wave-private

    const int tid = threadIdx.x, lane = tid & 63, w = tid >> 6;
    const int l = blockIdx.x;
    const int nb = l % 6;
    const int mt = l / 6;                 // 0..255
    const int m0 = mt * 128, n0 = nb * 128;
    const int m = lane & 15, quad = lane >> 4;

    // ---- stage W panel (256 x 128 fp32 -> bf16 fragment order), once ----
    {
        const int col = tid & 127;
        const int khalf = tid >> 7;
        #pragma unroll
        for (int s = 0; s < 32; ++s) {
            int k0 = (khalf + 2 * s) * 4;
            u16x4 h;
            #pragma unroll
            for (int i = 0; i < 4; ++i)
                h[i] = f2bf(Wq[(k0 + i) * 768 + n0 + col]);
            *(u16x4*)&Bs[((k0 >> 3) * 128 + col) * 8 + (k0 & 7)] = h;
        }
    }
    __syncthreads();   // the only block-wide barrier

    const int r = lane & 31, h = lane >> 5;
    const float* xrow = x + (size_t)(m0 + w * 32 + r) * 256 + h * 16;
    u16* As_w = &As[w][0];

    f32x4 acc[2][8];
    #pragma unroll
    for (int rt = 0; rt < 2; ++rt)
        #pragma unroll
        for (int ct = 0; ct < 8; ++ct)
            acc[rt][ct] = f32x4{0.f, 0.f, 0.f, 0.f};

    float4 g0 = *(const float4*)(xrow + 0);
    float4 g1 = *(const float4*)(xrow + 4);
    float4 g2 = *(const float4*)(xrow + 8);
    float4 g3 = *(const float4*)(xrow + 12);

    for (int kt = 0; kt < 8; ++kt) {
        u16x8 ha, hb;
        ha[0]=f2bf(g0.x); ha[1]=f2bf(g0.y); ha[2]=f2bf(g0.z); ha[3]=f2bf(g0.w);
        ha[4]=f2bf(g1.x); ha[5]=f2bf(g1.y); ha[6]=f2bf(g1.z); ha[7]=f2bf(g1.w);
        hb[0]=f2bf(g2.x); hb[1]=f2bf(g2.y); hb[2]=f2bf(g2.z); hb[3]=f2bf(g2.w);
        hb[4]=f2bf(g3.x); hb[5]=f2bf(g3.y); hb[6]=f2bf(g3.z); hb[7]=f2bf(g3.w);
        *(u16x8*)&As_w[r * 40 + h * 16]     = ha;
        *(u16x8*)&As_w[r * 40 + h * 16 + 8] = hb;

        if (kt < 7) {
            const float* xn = xrow + (kt + 1) * 32;
            g0 = *(const float4*)(xn + 0);
            g1 = *(const float4*)(xn + 4);
            g2 = *(const float4*)(xn + 8);
            g3 = *(const float4*)(xn + 12);
        }

        asm volatile("s_waitcnt lgkmcnt(0)" ::: "memory");

        bf16x8 af[2], bfr[8];
        #pragma unroll
        for (int rt = 0; rt < 2; ++rt)
            af[rt] = *(const bf16x8*)&As_w[(rt * 16 + m) * 40 + quad * 8];
        #pragma unroll
        for (int ct = 0; ct < 8; ++ct)
            bfr[ct] = *(const bf16x8*)&Bs[((kt * 4 + quad) * 128 + ct * 16 + m) * 8];
        #pragma unroll
        for (int rt = 0; rt < 2; ++rt)
            #pragma unroll
            for (int ct = 0; ct < 8; ++ct)
                acc[rt][ct] = __builtin_amdgcn_mfma_f32_16x16x32_bf16(
                    af[rt], bfr[ct], acc[rt][ct], 0, 0, 0);
    }

    const int b = m0 >> 12;
    const int jbase = (m0 & 4095) + w * 32;
    const int d0 = (nb & 1) * 128;

    if (nb < 2) {
        #pragma unroll
        for (int rt = 0; rt < 2; ++rt)
            #pragma unroll
            for (int ct = 0; ct < 8; ++ct) {
                int coll = ct * 16 + m;
                float bv = bias[d0 + coll];
                #pragma unroll
                for (int rr = 0; rr < 4; ++rr) {
                    int row = m0 + w * 32 + rt * 16 + quad * 4 + rr;
                    qb[(size_t)row * 256 + d0 + coll] = f2bf((acc[rt][ct][rr] + bv) * 0.0625f);
                }
            }
    } else if (nb < 4) {
        // K fragment-order w/ even-odd split: [b][jt][j&1][k8][qk*16 + (j>>1)][e]
        #pragma unroll
        for (int rt = 0; rt < 2; ++rt)
            #pragma unroll
            for (int ct = 0; ct < 8; ++ct) {
                int d = d0 + ct * 16 + m;
                float bv = bias[256 + d];
                int k8 = d >> 5, qk = (d >> 3) & 3, e = d & 7;
                #pragma unroll
                for (int rr = 0; rr < 4; ++rr) {
                    int j = jbase + rt * 16 + quad * 4 + rr;
                    int jt = j >> 5, jj = j & 31;
                    kb[((((size_t)(b * 128 + jt) * 2 + (jj & 1)) * 8 + k8) * 64 + qk * 16 + (jj >> 1)) * 8 + e]
                        = f2bf(acc[rt][ct][rr] + bv);
                }
            }
    } else {
        // V fragment-order: [b][jt][dt][qv*16+mv][e], e=j&7 -> u16x4 over rr
        #pragma unroll
        for (int rt = 0; rt < 2; ++rt)
            #pragma unroll
            for (int ct = 0; ct < 8; ++ct) {
                int d = d0 + ct * 16 + m;
                float bv = bias[512 + d];
                int dt = d >> 4, mv = d & 15;
                int j = jbase + rt * 16 + quad * 4;
                int jt = j >> 5, qv = (j >> 3) & 3, e0 = j & 7;
                u16x4 hv;
                #pragma unroll
                for (int rr = 0; rr < 4; ++rr) hv[rr] = f2bf(acc[rt][ct][rr] + bv);
                *(u16x4*)&vb[(((size_t)(b * 128 + jt) * 16 + dt) * 64 + qv * 16 + mv) * 8 + e0] = hv;
            }
    }
}

// ---------------------------------------------------------------------------
// Windowed flash-retention v9: counted-vmcnt deep pipeline (T3/T4 port).
// Diagnosis r0-r3: per-iter wall ~8500 cyc vs ~600 cyc compute; __syncthreads
// forces vmcnt(0) drain of 64 KB DMA every iter, and at 1 block/CU there is
// NO co-resident block to hide it -> ~90% stall, worse on high-latency
// containers. v9:
//   - K-only LDS ring, 3 buffers (96 KB): K(it+2) issued after barrier(it)
//     -> 2 iterations of latency budget. Ring WAR safe: issue-after-barrier
//     proves all waves finished reading that buffer.
//   - V bypasses LDS: 16 coalesced dwordx4 into registers at iter top,
//     consumed after QK (~600 cyc cover; 4 waves share tile via L2).
//   - raw s_barrier + counted s_waitcnt vmcnt(20/16/4/0) (wave-uniform),
//     never vmcnt(0) in steady state.
//   - combine epilogue in two 64 KB rounds (scratch = K ring).
// ---------------------------------------------------------------------------
__global__ __launch_bounds__(512, 2) void attn_kernel(
        const u16* __restrict__ qb, const u16* __restrict__ kb,
        const u16* __restrict__ vb, float* __restrict__ out)
{
    __shared__ __align__(16) u16 KR[3][2][8192];   // K ring: 3 bufs x 2 par, 96 KB
    __shared__ __align__(16) u16 Ps[8 * 32 * 40];  // per-wave P (32 rows), 20 KB

    const int tid = threadIdx.x, lane = tid & 63, w = tid >> 6;   // w 0..7
    const int wp = w & 3, par = w >> 2;           // row-group, tile-parity
    const int l = blockIdx.x;
    const int b = l & 7;
    const int m0 = (l >> 3) * 128;                // l>>3 in [0,32)
    const int qrow0 = m0 + wp * 32;
    const int m = lane & 15, quad = lane >> 4;
    const size_t rowbase = (size_t)b * 4096;
    const size_t pbase = (size_t)b * 128;

    bf16x8 qf[2][8];
    #pragma unroll
    for (int rg = 0; rg < 2; ++rg)
        #pragma unroll
        for (int k8 = 0; k8 < 8; ++k8)
            qf[rg][k8] = *(const bf16x8*)(qb + (rowbase + qrow0 + rg * 16 + m) * 256 + k8 * 32 + quad * 8);

    // loop-invariant decay factors: w0 = Arow * base(tile) * Em0, w1 = ... * Em1
    float Arow[2][4];
    #pragma unroll
    for (int rg = 0; rg < 2; ++rg)
        #pragma unroll
        for (int rr = 0; rr < 4; ++rr)
            Arow[rg][rr] = __builtin_amdgcn_exp2f((float)(rg * 16 + quad * 4 + rr) * L2ALPHA);
    const float Em0 = __builtin_amdgcn_exp2f((float)(-2 * m) * L2ALPHA);       // alpha^(-2m)
    const float Em1 = __builtin_amdgcn_exp2f((float)(-2 * m - 1) * L2ALPHA);   // alpha^(-2m-1)

    f32x4 acc[2][16];
    #pragma unroll
    for (int rg = 0; rg < 2; ++rg)
        #pragma unroll
        for (int dt = 0; dt < 16; ++dt)
            acc[rg][dt] = f32x4{0.f, 0.f, 0.f, 0.f};

    int t0 = (m0 - WIN) >> 5; if (t0 < 0) t0 = 0;
    const int t1 = (m0 >> 5) + 3;
    const int nIter = (t1 - t0 + 2) >> 1;         // tile count is always even

    // stage K for iteration itx into ring buffer itx%3 (4 gl2lds lines/thread)
    #define STAGE_K(itx)                                                    \
        do {                                                                \
            const int ta_ = t0 + 2 * (itx);                                 \
            const int buf_ = (itx) % 3;                                     \
            const u16* kpA_ = kb + (pbase + ta_) * 8192;                    \
            const u16* kpB_ = kpA_ + 8192;                                  \
            _Pragma("unroll")                                               \
            for (int s_ = 0; s_ < 2; ++s_) {                                \
                int c_ = tid + 512 * s_;                                    \
                gl2lds16(kpA_ + (size_t)c_ * 8, &KR[buf_][0][c_ * 8]);      \
                gl2lds16(kpB_ + (size_t)c_ * 8, &KR[buf_][1][c_ * 8]);      \
            }                                                               \
        } while (0)

    STAGE_K(0);
    STAGE_K(1);

    for (int it = 0; it < nIter; ++it) {
        const int t = t0 + 2 * it + par;
        const int j0 = t * 32;
        const bool valid = (t <= t1) && (j0 <= qrow0 + 31) && (j0 + (WIN + 31) >= qrow0);

        // V tile -> registers (issued before the K-wait; covered by QK phase)
        bf16x8 vf[16];
        if (valid) {
            const u16* Vg = vb + (pbase + (size_t)t) * 8192 + lane * 8;
            #pragma unroll
            for (int dt = 0; dt < 16; ++dt)
                vf[dt] = *(const bf16x8*)(Vg + dt * 512);
        }

        // retire this wave's K(it) DMA lines: allow newer ops to remain
        // outstanding (V this iter: 16, K(it+1): 4). Wave-uniform branches.
        if (valid) {
            if (it + 1 < nIter) asm volatile("s_waitcnt vmcnt(20)" ::: "memory");
            else                asm volatile("s_waitcnt vmcnt(16)" ::: "memory");
        } else {
            if (it + 1 < nIter) asm volatile("s_waitcnt vmcnt(4)" ::: "memory");
            else                asm volatile("s_waitcnt vmcnt(0)" ::: "memory");
        }
        __builtin_amdgcn_s_barrier();   // K(it) in LDS; buf (it+2)%3 retired

        if (it + 2 < nIter) STAGE_K(it + 2);   // 2-iteration prefetch depth

        if (valid) {
            const u16* Kt = &KR[it % 3][par][0];

            // tile-uniform decay base (off the MFMA critical path)
            const float base = __builtin_amdgcn_exp2f((float)(qrow0 - j0) * L2ALPHA);
            const float C0 = base * Em0, C1 = base * Em1;
            const bool diag = (j0 == qrow0);      // wave-uniform

            // S = q.k^T : even-key half and odd-key half, b-frag reused x2
            f32x4 sA0{0.f,0.f,0.f,0.f}, sA1{0.f,0.f,0.f,0.f};
            f32x4 sB0{0.f,0.f,0.f,0.f}, sB1{0.f,0.f,0.f,0.f};
            #pragma unroll
            for (int k8 = 0; k8 < 8; ++k8) {
                bf16x8 bf0 = *(const bf16x8*)&Kt[(k8 * 64 + lane) * 8];
                sA0 = __builtin_amdgcn_mfma_f32_16x16x32_bf16(qf[0][k8], bf0, sA0, 0, 0, 0);
                sA1 = __builtin_amdgcn_mfma_f32_16x16x32_bf16(qf[1][k8], bf0, sA1, 0, 0, 0);
            }
            #pragma unroll
            for (int k8 = 0; k8 < 8; ++k8) {
                bf16x8 bf1 = *(const bf16x8*)&Kt[((8 + k8) * 64 + lane) * 8];
                sB0 = __builtin_amdgcn_mfma_f32_16x16x32_bf16(qf[0][k8], bf1, sB0, 0, 0, 0);
                sB1 = __builtin_amdgcn_mfma_f32_16x16x32_bf16(qf[1][k8], bf1, sB1, 0, 0, 0);
            }

            // decay-mask; sA = even keys (j0+2m), sB = odd keys (j0+2m+1);
            // pack the adjacent-key pair as one u32 LDS write
            if (diag) {
                #pragma unroll
                for (int rg = 0; rg < 2; ++rg) {
                    f32x4 sh0 = rg ? sA1 : sA0;
                    f32x4 sh1 = rg ? sB1 : sB0;
                    #pragma unroll
                    for (int rr = 0; rr < 4; ++rr) {
                        int ioff = rg * 16 + quad * 4 + rr;
                        int dd0 = ioff - 2 * m;
                        float w0 = (dd0 >= 0) ? Arow[rg][rr] * C0 : 0.0f;
                        float w1 = (dd0 >= 1) ? Arow[rg][rr] * C1 : 0.0f;
                        int rowb = (w * 32 + ioff) * 40;
                        u32 pv = (u32)f2bf(sh0[rr] * w0) | ((u32)f2bf(sh1[rr] * w1) << 16);
                        *(u32*)&Ps[rowb + 2 * m] = pv;
                    }
                }
            } else {
                #pragma unroll
                for (int rg = 0; rg < 2; ++rg) {
                    f32x4 sh0 = rg ? sA1 : sA0;
                    f32x4 sh1 = rg ? sB1 : sB0;
                    #pragma unroll
                    for (int rr = 0; rr < 4; ++rr) {
                        int ioff = rg * 16 + quad * 4 + rr;
                        float w0 = Arow[rg][rr] * C0;
                        float w1 = Arow[rg][rr] * C1;
                        int rowb = (w * 32 + ioff) * 40;
                        u32 pv = (u32)f2bf(sh0[rr] * w0) | ((u32)f2bf(sh1[rr] * w1) << 16);
                        *(u32*)&Ps[rowb + 2 * m] = pv;
                    }
                }
            }
            asm volatile("s_waitcnt lgkmcnt(0)" ::: "memory");  // wave-local P ready

            bf16x8 pa0 = *(const bf16x8*)&Ps[(w * 32 + m) * 40 + quad * 8];
            bf16x8 pa1 = *(const bf16x8*)&Ps[(w * 32 + 16 + m) * 40 + quad * 8];

            #pragma unroll
            for (int dt = 0; dt < 16; ++dt) {
                acc[0][dt] = __builtin_amdgcn_mfma_f32_16x16x32_bf16(pa0, vf[dt], acc[0][dt], 0, 0, 0);
                acc[1][dt] = __builtin_amdgcn_mfma_f32_16x16x32_bf16(pa1, vf[dt], acc[1][dt], 0, 0, 0);
            }
        }
    }

    // in-block combine via retired K ring (96 KB scratch), two 64 KB rounds.
    // slot index XOR-swizzled by (lane&7) (lane stride 64 floats is
    // bank-aligned; swizzle spreads each 8-lane group across banks).
    asm volatile("s_waitcnt lgkmcnt(0)" ::: "memory");
    __builtin_amdgcn_s_barrier();                 // all waves done with KR
    float* Comb = (float*)&KR[0][0][0];
    #pragma unroll
    for (int rg = 0; rg < 2; ++rg) {
        if (par == 1) {
            float* dst = Comb + (size_t)wp * 4096 + lane * 64;
            #pragma unroll
            for (int dt = 0; dt < 16; ++dt)
                *(f32x4*)(dst + (dt ^ (lane & 7)) * 4) = acc[rg][dt];
        }
        asm volatile("s_waitcnt lgkmcnt(0)" ::: "memory");
        __builtin_amdgcn_s_barrier();
        if (par == 0) {
            const float* src = Comb + (size_t)wp * 4096 + lane * 64;
            #pragma unroll
            for (int dt = 0; dt < 16; ++dt) {
                f32x4 o = acc[rg][dt] + *(const f32x4*)(src + (dt ^ (lane & 7)) * 4);
                #pragma unroll
                for (int rr = 0; rr < 4; ++rr)
                    out[(rowbase + qrow0 + rg * 16 + quad * 4 + rr) * 256 + dt * 16 + m] = o[rr];
            }
        }
        if (rg == 0) {
            asm volatile("s_waitcnt lgkmcnt(0)" ::: "memory");
            __builtin_amdgcn_s_barrier();         // round-0 reads done before round-1 writes
        }
    }
}

// ---------------------------------------------------------------------------
extern "C" void kernel_launch(void* const* d_in, const int* in_sizes, int n_in,
                              void* d_out, int out_size, void* d_ws, size_t ws_size,
                              hipStream_t stream) {
    (void)in_sizes; (void)n_in; (void)out_size; (void)ws_size;
    const float* x    = (const float*)d_in[0];
    const float* Wq   = (const float*)d_in[1];
    const float* bias = (const float*)d_in[2];
    float* outp = (float*)d_out;

    const size_t per = (size_t)8 * 4096 * 256;   // elems per q/k/v buffer (48 MB total)
    u16* qb = (u16*)d_ws;
    u16* kb = qb + per;
    u16* vb = kb + per;

    proj_kernel<<<1536, 256, 0, stream>>>(x, Wq, bias, qb, kb, vb);
    attn_kernel<<<256, 512, 0, stream>>>(qb, kb, vb, outp);
}

// Round 5
// 176.597 us; speedup vs baseline: 2.1589x; 2.1589x over previous
//
#include <hip/hip_runtime.h>

typedef __bf16 bf16x8 __attribute__((ext_vector_type(8)));
typedef float f32x4 __attribute__((ext_vector_type(4)));
typedef unsigned short u16;
typedef unsigned int u32;
typedef u16 u16x4 __attribute__((ext_vector_type(4)));
typedef u16 u16x8 __attribute__((ext_vector_type(8)));

#define L2ALPHA (-0.014499569f)   // log2(0.99)
#define WIN 1024                  // decay window

static __device__ __forceinline__ u16 f2bf(float f) {
    u32 u = __builtin_bit_cast(u32, f);
    return (u16)((u + 0x7FFFu + ((u >> 16) & 1u)) >> 16);
}

// async global->LDS, 16B per lane, dest must be wave-uniform-base + lane*16
static __device__ __forceinline__ void gl2lds16(const void* g, void* l) {
    __builtin_amdgcn_global_load_lds(
        (const __attribute__((address_space(1))) u32*)g,
        (__attribute__((address_space(3))) u32*)l, 16, 0, 0);
}

// ---------------------------------------------------------------------------
// Projection v4 (unchanged): one barrier total; W panel staged once;
// x staged wave-private each kt. K panel stored with EVEN/ODD key split.
// ---------------------------------------------------------------------------
__global__ __launch_bounds__(256, 2) void proj_kernel(
        const float* __restrict__ x, const float* __restrict__ Wq,
        const float* __restrict__ bias,
        u16* __restrict__ qb, u16* __restrict__ kb, u16* __restrict__ vb)
{
    __shared__ __align__(16) u16 Bs[32 * 128 * 8];   // 64 KB: [k8][col][e]
    __shared__ __align__(16) u16 As[4][32 * 40];     // 10 KB, wave-private

    const int tid = threadIdx.x, lane = tid & 63, w = tid >> 6;
    const int l = blockIdx.x;
    const int nb = l % 6;
    const int mt = l / 6;                 // 0..255
    const int m0 = mt * 128, n0 = nb * 128;
    const int m = lane & 15, quad = lane >> 4;

    // ---- stage W panel (256 x 128 fp32 -> bf16 fragment order), once ----
    {
        const int col = tid & 127;
        const int khalf = tid >> 7;
        #pragma unroll
        for (int s = 0; s < 32; ++s) {
            int k0 = (khalf + 2 * s) * 4;
            u16x4 h;
            #pragma unroll
            for (int i = 0; i < 4; ++i)
                h[i] = f2bf(Wq[(k0 + i) * 768 + n0 + col]);
            *(u16x4*)&Bs[((k0 >> 3) * 128 + col) * 8 + (k0 & 7)] = h;
        }
    }
    __syncthreads();   // the only block-wide barrier

    const int r = lane & 31, h = lane >> 5;
    const float* xrow = x + (size_t)(m0 + w * 32 + r) * 256 + h * 16;
    u16* As_w = &As[w][0];

    f32x4 acc[2][8];
    #pragma unroll
    for (int rt = 0; rt < 2; ++rt)
        #pragma unroll
        for (int ct = 0; ct < 8; ++ct)
            acc[rt][ct] = f32x4{0.f, 0.f, 0.f, 0.f};

    float4 g0 = *(const float4*)(xrow + 0);
    float4 g1 = *(const float4*)(xrow + 4);
    float4 g2 = *(const float4*)(xrow + 8);
    float4 g3 = *(const float4*)(xrow + 12);

    for (int kt = 0; kt < 8; ++kt) {
        u16x8 ha, hb;
        ha[0]=f2bf(g0.x); ha[1]=f2bf(g0.y); ha[2]=f2bf(g0.z); ha[3]=f2bf(g0.w);
        ha[4]=f2bf(g1.x); ha[5]=f2bf(g1.y); ha[6]=f2bf(g1.z); ha[7]=f2bf(g1.w);
        hb[0]=f2bf(g2.x); hb[1]=f2bf(g2.y); hb[2]=f2bf(g2.z); hb[3]=f2bf(g2.w);
        hb[4]=f2bf(g3.x); hb[5]=f2bf(g3.y); hb[6]=f2bf(g3.z); hb[7]=f2bf(g3.w);
        *(u16x8*)&As_w[r * 40 + h * 16]     = ha;
        *(u16x8*)&As_w[r * 40 + h * 16 + 8] = hb;

        if (kt < 7) {
            const float* xn = xrow + (kt + 1) * 32;
            g0 = *(const float4*)(xn + 0);
            g1 = *(const float4*)(xn + 4);
            g2 = *(const float4*)(xn + 8);
            g3 = *(const float4*)(xn + 12);
        }

        asm volatile("s_waitcnt lgkmcnt(0)" ::: "memory");

        bf16x8 af[2], bfr[8];
        #pragma unroll
        for (int rt = 0; rt < 2; ++rt)
            af[rt] = *(const bf16x8*)&As_w[(rt * 16 + m) * 40 + quad * 8];
        #pragma unroll
        for (int ct = 0; ct < 8; ++ct)
            bfr[ct] = *(const bf16x8*)&Bs[((kt * 4 + quad) * 128 + ct * 16 + m) * 8];
        #pragma unroll
        for (int rt = 0; rt < 2; ++rt)
            #pragma unroll
            for (int ct = 0; ct < 8; ++ct)
                acc[rt][ct] = __builtin_amdgcn_mfma_f32_16x16x32_bf16(
                    af[rt], bfr[ct], acc[rt][ct], 0, 0, 0);
    }

    const int b = m0 >> 12;
    const int jbase = (m0 & 4095) + w * 32;
    const int d0 = (nb & 1) * 128;

    if (nb < 2) {
        #pragma unroll
        for (int rt = 0; rt < 2; ++rt)
            #pragma unroll
            for (int ct = 0; ct < 8; ++ct) {
                int coll = ct * 16 + m;
                float bv = bias[d0 + coll];
                #pragma unroll
                for (int rr = 0; rr < 4; ++rr) {
                    int row = m0 + w * 32 + rt * 16 + quad * 4 + rr;
                    qb[(size_t)row * 256 + d0 + coll] = f2bf((acc[rt][ct][rr] + bv) * 0.0625f);
                }
            }
    } else if (nb < 4) {
        // K fragment-order w/ even-odd split: [b][jt][j&1][k8][qk*16 + (j>>1)][e]
        #pragma unroll
        for (int rt = 0; rt < 2; ++rt)
            #pragma unroll
            for (int ct = 0; ct < 8; ++ct) {
                int d = d0 + ct * 16 + m;
                float bv = bias[256 + d];
                int k8 = d >> 5, qk = (d >> 3) & 3, e = d & 7;
                #pragma unroll
                for (int rr = 0; rr < 4; ++rr) {
                    int j = jbase + rt * 16 + quad * 4 + rr;
                    int jt = j >> 5, jj = j & 31;
                    kb[((((size_t)(b * 128 + jt) * 2 + (jj & 1)) * 8 + k8) * 64 + qk * 16 + (jj >> 1)) * 8 + e]
                        = f2bf(acc[rt][ct][rr] + bv);
                }
            }
    } else {
        // V fragment-order: [b][jt][dt][qv*16+mv][e], e=j&7 -> u16x4 over rr
        #pragma unroll
        for (int rt = 0; rt < 2; ++rt)
            #pragma unroll
            for (int ct = 0; ct < 8; ++ct) {
                int d = d0 + ct * 16 + m;
                float bv = bias[512 + d];
                int dt = d >> 4, mv = d & 15;
                int j = jbase + rt * 16 + quad * 4;
                int jt = j >> 5, qv = (j >> 3) & 3, e0 = j & 7;
                u16x4 hv;
                #pragma unroll
                for (int rr = 0; rr < 4; ++rr) hv[rr] = f2bf(acc[rt][ct][rr] + bv);
                *(u16x4*)&vb[(((size_t)(b * 128 + jt) * 16 + dt) * 64 + qv * 16 + mv) * 8 + e0] = hv;
            }
    }
}

// ---------------------------------------------------------------------------
// Windowed flash-retention v10: 1 tile/iter, 4-deep LDS ring, counted vmcnt.
// Post-mortem v9: V-in-registers spilled (qf64+vf64+acc128 > 256 budget) ->
// 289 MB scratch WRITE. v10 gets pipeline depth from LDS instead:
//   - 8 waves x 16 q-rows (no t-parity): per-iter footprint = ONE 32-key tile
//     (K 16KB + V 16KB) -> 4-deep ring = 128 KB + Ps 10 KB fits LDS.
//   - stage(it) issued 3 iterations ahead (~1200+ cyc budget >= HBM miss);
//     steady-state wait is s_waitcnt vmcnt(8), NEVER 0; raw s_barrier.
//   - no partial-combine epilogue (each wave owns its 16 rows end-to-end);
//     acc 64 AGPR + qf 32 VGPR -> no spill possible.
// ---------------------------------------------------------------------------
__global__ __launch_bounds__(512, 2) void attn_kernel(
        const u16* __restrict__ qb, const u16* __restrict__ kb,
        const u16* __restrict__ vb, float* __restrict__ out)
{
    __shared__ __align__(16) u16 RB[4][16384];     // ring: [K even|odd 16KB][V 16KB]
    __shared__ __align__(16) u16 Ps[8 * 16 * 40];  // per-wave P (16 rows), 10 KB

    const int tid = threadIdx.x, lane = tid & 63, w = tid >> 6;   // w 0..7
    const int l = blockIdx.x;
    const int b = l & 7;
    const int m0 = (l >> 3) * 128;                // l>>3 in [0,32)
    const int qrow0 = m0 + w * 16;                // wave-private 16 rows
    const int m = lane & 15, quad = lane >> 4;
    const size_t rowbase = (size_t)b * 4096;
    const size_t pbase = (size_t)b * 128;

    // Q fragments (16 rows x 256 dims)
    bf16x8 qf[8];
    #pragma unroll
    for (int k8 = 0; k8 < 8; ++k8)
        qf[k8] = *(const bf16x8*)(qb + (rowbase + qrow0 + m) * 256 + k8 * 32 + quad * 8);
    // retire q loads BEFORE any DMA is issued so no q-wait lands in the loop
    asm volatile("s_waitcnt vmcnt(0)" ::: "memory");

    // loop-invariant decay factors: w = Arow[ioff] * base(tile) * Em{0,1}
    float Arow[4];
    #pragma unroll
    for (int rr = 0; rr < 4; ++rr)
        Arow[rr] = __builtin_amdgcn_exp2f((float)(quad * 4 + rr) * L2ALPHA);
    const float Em0 = __builtin_amdgcn_exp2f((float)(-2 * m) * L2ALPHA);
    const float Em1 = __builtin_amdgcn_exp2f((float)(-2 * m - 1) * L2ALPHA);

    f32x4 acc[16];
    #pragma unroll
    for (int dt = 0; dt < 16; ++dt)
        acc[dt] = f32x4{0.f, 0.f, 0.f, 0.f};

    int t0 = (m0 - WIN) >> 5; if (t0 < 0) t0 = 0;
    const int t1 = (m0 >> 5) + 3;
    const int nT = t1 - t0 + 1;                   // 4..36 tiles

    // stage tile (t0+ix) into ring slot ix&3: 4 DMA lines/thread (K 2, V 2)
    #define STAGE(ix)                                                       \
        do {                                                                \
            const int buf_ = (ix) & 3;                                      \
            const u16* kp_ = kb + (pbase + t0 + (ix)) * 8192;               \
            const u16* vp_ = vb + (pbase + t0 + (ix)) * 8192;               \
            _Pragma("unroll")                                               \
            for (int s_ = 0; s_ < 2; ++s_) {                                \
                int c_ = tid + 512 * s_;                                    \
                gl2lds16(kp_ + (size_t)c_ * 8, &RB[buf_][c_ * 8]);          \
                gl2lds16(vp_ + (size_t)c_ * 8, &RB[buf_][8192 + c_ * 8]);   \
            }                                                               \
        } while (0)

    STAGE(0); STAGE(1); STAGE(2);                 // nT >= 4 always

    for (int it = 0; it < nT; ++it) {
        // retire stage(it); keep stage(it+1), stage(it+2) in flight (4 each)
        if (it <= nT - 3)      asm volatile("s_waitcnt vmcnt(8)" ::: "memory");
        else if (it == nT - 2) asm volatile("s_waitcnt vmcnt(4)" ::: "memory");
        else                   asm volatile("s_waitcnt vmcnt(0)" ::: "memory");
        __builtin_amdgcn_s_barrier();             // all waves' stage(it) landed
        asm volatile("" ::: "memory");            // pin ds_reads below barrier

        if (it + 3 < nT) STAGE(it + 3);           // slot (it+3)&3 = (it-1)&3: retired

        const int t = t0 + it;
        const int j0 = t * 32;
        // wave-uniform: tile not all-future and within decay window
        if (j0 <= qrow0 + 15 && j0 + (WIN + 31) >= qrow0) {
            const u16* Kt = &RB[it & 3][0];
            const u16* Vt = &RB[it & 3][8192];

            const float base = __builtin_amdgcn_exp2f((float)(qrow0 - j0) * L2ALPHA);
            const float C0 = base * Em0, C1 = base * Em1;
            const bool needMask = (j0 + 31 > qrow0);   // wave-uniform

            // S = q.k^T : even keys (j0+2m) and odd keys (j0+2m+1)
            f32x4 sA{0.f,0.f,0.f,0.f}, sB{0.f,0.f,0.f,0.f};
            #pragma unroll
            for (int k8 = 0; k8 < 8; ++k8) {
                bf16x8 bf0 = *(const bf16x8*)&Kt[(k8 * 64 + lane) * 8];
                sA = __builtin_amdgcn_mfma_f32_16x16x32_bf16(qf[k8], bf0, sA, 0, 0, 0);
            }
            #pragma unroll
            for (int k8 = 0; k8 < 8; ++k8) {
                bf16x8 bf1 = *(const bf16x8*)&Kt[((8 + k8) * 64 + lane) * 8];
                sB = __builtin_amdgcn_mfma_f32_16x16x32_bf16(qf[k8], bf1, sB, 0, 0, 0);
            }

            // decay-mask + pack adjacent-key pair as one u32 LDS write
            if (needMask) {
                #pragma unroll
                for (int rr = 0; rr < 4; ++rr) {
                    int ioff = quad * 4 + rr;
                    int dd0 = (qrow0 - j0) + ioff - 2 * m;
                    float w0 = (dd0 >= 0) ? Arow[rr] * C0 : 0.0f;
                    float w1 = (dd0 >= 1) ? Arow[rr] * C1 : 0.0f;
                    u32 pv = (u32)f2bf(sA[rr] * w0) | ((u32)f2bf(sB[rr] * w1) << 16);
                    *(u32*)&Ps[(w * 16 + ioff) * 40 + 2 * m] = pv;
                }
            } else {
                #pragma unroll
                for (int rr = 0; rr < 4; ++rr) {
                    int ioff = quad * 4 + rr;
                    float w0 = Arow[rr] * C0;
                    float w1 = Arow[rr] * C1;
                    u32 pv = (u32)f2bf(sA[rr] * w0) | ((u32)f2bf(sB[rr] * w1) << 16);
                    *(u32*)&Ps[(w * 16 + ioff) * 40 + 2 * m] = pv;
                }
            }
            asm volatile("s_waitcnt lgkmcnt(0)" ::: "memory");  // wave-local P ready

            bf16x8 pa = *(const bf16x8*)&Ps[(w * 16 + m) * 40 + quad * 8];

            #pragma unroll
            for (int dt = 0; dt < 16; ++dt) {
                bf16x8 vf = *(const bf16x8*)&Vt[(dt * 64 + lane) * 8];
                acc[dt] = __builtin_amdgcn_mfma_f32_16x16x32_bf16(pa, vf, acc[dt], 0, 0, 0);
            }
        }
    }

    // direct epilogue: each wave owns rows [qrow0, qrow0+16)
    #pragma unroll
    for (int dt = 0; dt < 16; ++dt)
        #pragma unroll
        for (int rr = 0; rr < 4; ++rr)
            out[(rowbase + qrow0 + quad * 4 + rr) * 256 + dt * 16 + m] = acc[dt][rr];
}

// ---------------------------------------------------------------------------
extern "C" void kernel_launch(void* const* d_in, const int* in_sizes, int n_in,
                              void* d_out, int out_size, void* d_ws, size_t ws_size,
                              hipStream_t stream) {
    (void)in_sizes; (void)n_in; (void)out_size; (void)ws_size;
    const float* x    = (const float*)d_in[0];
    const float* Wq   = (const float*)d_in[1];
    const float* bias = (const float*)d_in[2];
    float* outp = (float*)d_out;

    const size_t per = (size_t)8 * 4096 * 256;   // elems per q/k/v buffer (48 MB total)
    u16* qb = (u16*)d_ws;
    u16* kb = qb + per;
    u16* vb = kb + per;

    proj_kernel<<<1536, 256, 0, stream>>>(x, Wq, bias, qb, kb, vb);
    attn_kernel<<<256, 512, 0, stream>>>(qb, kb, vb, outp);
}